// Round 1
// baseline (12463.567 us; speedup 1.0000x reference)
//
#include <hip/hip_runtime.h>

#define NN 100000
#define NE 1600000
#define FD 128
#define NC 10
#define NG 64

__global__ void k_init_deg(float* __restrict__ deg) {
  int i = blockIdx.x * 256 + threadIdx.x;
  if (i < NN) deg[i] = 1.0f;   // self-loop contributes 1
}

__global__ void k_count_deg(const int* __restrict__ dst, float* __restrict__ deg) {
  int e = blockIdx.x * 256 + threadIdx.x;
  if (e < NE) atomicAdd(&deg[dst[e]], 1.0f);
}

__global__ void k_dinv(float* __restrict__ deg) {
  int i = blockIdx.x * 256 + threadIdx.x;
  if (i < NN) deg[i] = 1.0f / sqrtf(deg[i]);
}

__global__ void k_norm(const int* __restrict__ src, const int* __restrict__ dst,
                       const float* __restrict__ dinv, float* __restrict__ norm) {
  int e = blockIdx.x * 256 + threadIdx.x;
  if (e < NE) norm[e] = dinv[src[e]] * dinv[dst[e]];
}

// H[row, col] = sum_k X[row, k] * W[k, col]   (naive: 1 output/thread, cache-fed)
__global__ void k_gemm(const float* __restrict__ X, const float* __restrict__ W,
                       float* __restrict__ H) {
  int t = blockIdx.x * 256 + threadIdx.x;
  if (t >= NN * FD) return;
  int row = t >> 7, col = t & 127;
  const float4* __restrict__ xv = (const float4*)(X + (size_t)row * FD);
  float acc = 0.f;
#pragma unroll 4
  for (int k4 = 0; k4 < FD / 4; ++k4) {
    float4 v = xv[k4];
    int k = k4 * 4;
    acc = fmaf(v.x, W[(k + 0) * FD + col], acc);
    acc = fmaf(v.y, W[(k + 1) * FD + col], acc);
    acc = fmaf(v.z, W[(k + 2) * FD + col], acc);
    acc = fmaf(v.w, W[(k + 3) * FD + col], acc);
  }
  H[t] = acc;
}

// AGG = dinv^2 * H + b   (self-loop term + bias; also zero-inits the scatter target)
__global__ void k_init_agg(const float* __restrict__ H, const float* __restrict__ dinv,
                           const float* __restrict__ b, float* __restrict__ AGG) {
  int t = blockIdx.x * 256 + threadIdx.x;
  if (t >= NN * FD) return;
  int i = t >> 7, f = t & 127;
  float di = dinv[i];
  AGG[t] = di * di * H[t] + b[f];
}

// AGG[dst] += norm[e] * H[src]; 32 threads/edge, 4 feats each
__global__ void k_scatter(const int* __restrict__ src, const int* __restrict__ dst,
                          const float* __restrict__ norm, const float* __restrict__ H,
                          float* __restrict__ AGG) {
  int t = blockIdx.x * 256 + threadIdx.x;
  int e = t >> 5;
  if (e >= NE) return;
  int f0 = (t & 31) << 2;
  int s = src[e], d = dst[e];
  float w = norm[e];
  float4 hv = *(const float4*)(H + (size_t)s * FD + f0);
  float* a = AGG + (size_t)d * FD + f0;
  atomicAdd(a + 0, hv.x * w);
  atomicAdd(a + 1, hv.y * w);
  atomicAdd(a + 2, hv.z * w);
  atomicAdd(a + 3, hv.w * w);
}

__global__ void k_relu(float* __restrict__ A) {
  int t = blockIdx.x * 256 + threadIdx.x;
  if (t < NN * FD) A[t] = fmaxf(A[t], 0.f);
}

__global__ void k_zero_pool(float* __restrict__ sums, float* __restrict__ counts) {
  int t = blockIdx.x * 256 + threadIdx.x;
  if (t < NG * FD) sums[t] = 0.f;
  if (t < NG) counts[t] = 0.f;
}

// batch is sorted: each block sums a contiguous node chunk locally, flushing
// an atomic only when the graph id changes (~2 flushes/chunk).
#define POOL_BLOCKS 1024
#define POOL_CHUNK 98   // 1024*98 = 100352 >= NN
__global__ void k_pool(const int* __restrict__ batch, const float* __restrict__ H,
                       float* __restrict__ sums, float* __restrict__ counts) {
  int f = threadIdx.x;  // 0..127
  int i0 = blockIdx.x * POOL_CHUNK;
  if (i0 >= NN) return;
  int i1 = i0 + POOL_CHUNK;
  if (i1 > NN) i1 = NN;
  float acc = 0.f;
  int gcur = batch[i0];
  int cnt = 0;
  for (int i = i0; i < i1; ++i) {
    int g = batch[i];
    if (g != gcur) {
      atomicAdd(&sums[gcur * FD + f], acc);
      if (f == 0) atomicAdd(&counts[gcur], (float)cnt);
      acc = 0.f; cnt = 0; gcur = g;
    }
    acc += H[(size_t)i * FD + f];
    ++cnt;
  }
  atomicAdd(&sums[gcur * FD + f], acc);
  if (f == 0) atomicAdd(&counts[gcur], (float)cnt);
}

// out[g, c] = (sums[g,:]/max(count,1)) @ W_mlp + b_mlp
__global__ void k_head(const float* __restrict__ sums, const float* __restrict__ counts,
                       const float* __restrict__ Wm, const float* __restrict__ bm,
                       float* __restrict__ out) {
  int t = blockIdx.x * 256 + threadIdx.x;
  if (t >= NG * NC) return;
  int g = t / NC, c = t % NC;
  float inv = 1.0f / fmaxf(counts[g], 1.0f);
  float s = 0.f;
#pragma unroll 4
  for (int f = 0; f < FD; ++f) s = fmaf(sums[g * FD + f] * inv, Wm[f * NC + c], s);
  out[t] = s + bm[c];
}

extern "C" void kernel_launch(void* const* d_in, const int* in_sizes, int n_in,
                              void* d_out, int out_size, void* d_ws, size_t ws_size,
                              hipStream_t stream) {
  const float* x     = (const float*)d_in[0];
  const int*   ei    = (const int*)d_in[1];
  const int*   batch = (const int*)d_in[2];
  const float* W_in  = (const float*)d_in[3];
  const float* b_in  = (const float*)d_in[4];
  const float* W_mid = (const float*)d_in[5];
  const float* b_mid = (const float*)d_in[6];
  const float* W_mlp = (const float*)d_in[7];
  const float* b_mlp = (const float*)d_in[8];
  float* out = (float*)d_out;

  const int* src = ei;        // edge_index[0]
  const int* dst = ei + NE;   // edge_index[1]

  float* ws     = (float*)d_ws;
  float* P      = ws;                          // NN*FD
  float* Q      = P + (size_t)NN * FD;         // NN*FD
  float* dinv   = Q + (size_t)NN * FD;         // NN
  float* norm   = dinv + NN;                   // NE
  float* sums   = norm + NE;                   // NG*FD
  float* counts = sums + NG * FD;              // NG
  // total ~109.2 MB of d_ws

  k_init_deg<<<(NN + 255) / 256, 256, 0, stream>>>(dinv);
  k_count_deg<<<(NE + 255) / 256, 256, 0, stream>>>(dst, dinv);
  k_dinv<<<(NN + 255) / 256, 256, 0, stream>>>(dinv);
  k_norm<<<(NE + 255) / 256, 256, 0, stream>>>(src, dst, dinv, norm);

  const int gN = (NN * FD + 255) / 256;     // 50000
  const int gE = (NE * 32 + 255) / 256;     // 200000
  for (int L = 0; L < 4; ++L) {
    const float* X = (L == 0) ? x : P;
    const float* W = (L == 0) ? W_in : W_mid;
    const float* b = (L == 0) ? b_in : b_mid;
    k_gemm<<<gN, 256, 0, stream>>>(X, W, Q);
    k_init_agg<<<gN, 256, 0, stream>>>(Q, dinv, b, P);
    k_scatter<<<gE, 256, 0, stream>>>(src, dst, norm, Q, P);
    k_relu<<<gN, 256, 0, stream>>>(P);
  }

  k_zero_pool<<<32, 256, 0, stream>>>(sums, counts);
  k_pool<<<POOL_BLOCKS, 128, 0, stream>>>(batch, P, sums, counts);
  k_head<<<(NG * NC + 255) / 256, 256, 0, stream>>>(sums, counts, W_mlp, b_mlp, out);
}

// Round 2
// 2565.331 us; speedup vs baseline: 4.8585x; 4.8585x over previous
//
#include <hip/hip_runtime.h>

#define NN 100000
#define NE 1600000
#define FD 128
#define NC 10
#define NG 64

// ---------- CSR build ----------

__global__ void k_zero_int(int* __restrict__ a, int n) {
  int i = blockIdx.x * 256 + threadIdx.x;
  if (i < n) a[i] = 0;
}

__global__ void k_count(const int* __restrict__ dst, int* __restrict__ cnt) {
  int e = blockIdx.x * 256 + threadIdx.x;
  if (e < NE) atomicAdd(&cnt[dst[e]], 1);
}

// Single-block exclusive scan of in-degree counts -> rowptr; also emits
// dinv[i] = 1/sqrt(deg+1) and zeroes the counts buffer for reuse as cursor.
#define SCAN_T 1024
#define SCAN_CHUNK 98  // 1024*98 = 100352 >= NN
__global__ void k_scan(int* __restrict__ cnt, int* __restrict__ rowptr,
                       float* __restrict__ dinv) {
  __shared__ int part[SCAN_T];
  int t = threadIdx.x;
  int c0 = t * SCAN_CHUNK;
  int c1 = c0 + SCAN_CHUNK; if (c1 > NN) c1 = NN;
  int s = 0;
  for (int i = c0; i < c1; ++i) s += cnt[i];
  part[t] = s;
  __syncthreads();
  for (int off = 1; off < SCAN_T; off <<= 1) {
    int v = (t >= off) ? part[t - off] : 0;
    __syncthreads();
    part[t] += v;
    __syncthreads();
  }
  int run = (t == 0) ? 0 : part[t - 1];
  for (int i = c0; i < c1; ++i) {
    int c = cnt[i];
    rowptr[i] = run;
    dinv[i] = rsqrtf((float)c + 1.0f);
    cnt[i] = 0;           // becomes the fill cursor
    run += c;
  }
  if (t == SCAN_T - 1) rowptr[NN] = run;
}

__global__ void k_fill(const int* __restrict__ src, const int* __restrict__ dst,
                       const int* __restrict__ rowptr, int* __restrict__ cursor,
                       int* __restrict__ csr_src) {
  int e = blockIdx.x * 256 + threadIdx.x;
  if (e >= NE) return;
  int d = dst[e];
  int slot = rowptr[d] + atomicAdd(&cursor[d], 1);
  csr_src[slot] = src[e];
}

// ---------- per-layer kernels ----------

// H[row, col] = sum_k X[row, k] * W[k, col]
__global__ void k_gemm(const float* __restrict__ X, const float* __restrict__ W,
                       float* __restrict__ H) {
  int t = blockIdx.x * 256 + threadIdx.x;
  if (t >= NN * FD) return;
  int row = t >> 7, col = t & 127;
  const float4* __restrict__ xv = (const float4*)(X + (size_t)row * FD);
  float acc = 0.f;
#pragma unroll 4
  for (int k4 = 0; k4 < FD / 4; ++k4) {
    float4 v = xv[k4];
    int k = k4 * 4;
    acc = fmaf(v.x, W[(k + 0) * FD + col], acc);
    acc = fmaf(v.y, W[(k + 1) * FD + col], acc);
    acc = fmaf(v.z, W[(k + 2) * FD + col], acc);
    acc = fmaf(v.w, W[(k + 3) * FD + col], acc);
  }
  H[t] = acc;
}

// One wave (64 lanes) per node; 2 feats per lane (float2 = 8B -> 512B/row/wave).
// OUT[i] = relu( dinv[i]^2 * H[i] + b + sum_{e in CSR row i} dinv[s]*dinv[i]*H[s] )
__global__ void k_gather(const int* __restrict__ rowptr, const int* __restrict__ csr_src,
                         const float* __restrict__ dinv, const float* __restrict__ H,
                         const float* __restrict__ b, float* __restrict__ OUT) {
  int node = blockIdx.x * 4 + (threadIdx.x >> 6);
  if (node >= NN) return;
  int lane = threadIdx.x & 63;
  float di = dinv[node];
  float2 hv = ((const float2*)(H + (size_t)node * FD))[lane];
  float2 bv = ((const float2*)b)[lane];
  float2 acc;
  acc.x = di * di * hv.x + bv.x;
  acc.y = di * di * hv.y + bv.y;
  int e0 = rowptr[node], e1 = rowptr[node + 1];
  for (int e = e0; e < e1; ++e) {
    int s = csr_src[e];
    float w = dinv[s] * di;
    float2 v = ((const float2*)(H + (size_t)s * FD))[lane];
    acc.x = fmaf(w, v.x, acc.x);
    acc.y = fmaf(w, v.y, acc.y);
  }
  acc.x = fmaxf(acc.x, 0.f);
  acc.y = fmaxf(acc.y, 0.f);
  ((float2*)(OUT + (size_t)node * FD))[lane] = acc;
}

// ---------- pooling + head ----------

__global__ void k_zero_pool(float* __restrict__ sums, float* __restrict__ counts) {
  int t = blockIdx.x * 256 + threadIdx.x;
  if (t < NG * FD) sums[t] = 0.f;
  if (t < NG) counts[t] = 0.f;
}

#define POOL_BLOCKS 1024
#define POOL_CHUNK 98
__global__ void k_pool(const int* __restrict__ batch, const float* __restrict__ H,
                       float* __restrict__ sums, float* __restrict__ counts) {
  int f = threadIdx.x;  // 0..127
  int i0 = blockIdx.x * POOL_CHUNK;
  if (i0 >= NN) return;
  int i1 = i0 + POOL_CHUNK;
  if (i1 > NN) i1 = NN;
  float acc = 0.f;
  int gcur = batch[i0];
  int cnt = 0;
  for (int i = i0; i < i1; ++i) {
    int g = batch[i];
    if (g != gcur) {
      atomicAdd(&sums[gcur * FD + f], acc);
      if (f == 0) atomicAdd(&counts[gcur], (float)cnt);
      acc = 0.f; cnt = 0; gcur = g;
    }
    acc += H[(size_t)i * FD + f];
    ++cnt;
  }
  atomicAdd(&sums[gcur * FD + f], acc);
  if (f == 0) atomicAdd(&counts[gcur], (float)cnt);
}

__global__ void k_head(const float* __restrict__ sums, const float* __restrict__ counts,
                       const float* __restrict__ Wm, const float* __restrict__ bm,
                       float* __restrict__ out) {
  int t = blockIdx.x * 256 + threadIdx.x;
  if (t >= NG * NC) return;
  int g = t / NC, c = t % NC;
  float inv = 1.0f / fmaxf(counts[g], 1.0f);
  float s = 0.f;
#pragma unroll 4
  for (int f = 0; f < FD; ++f) s = fmaf(sums[g * FD + f] * inv, Wm[f * NC + c], s);
  out[t] = s + bm[c];
}

extern "C" void kernel_launch(void* const* d_in, const int* in_sizes, int n_in,
                              void* d_out, int out_size, void* d_ws, size_t ws_size,
                              hipStream_t stream) {
  const float* x     = (const float*)d_in[0];
  const int*   ei    = (const int*)d_in[1];
  const int*   batch = (const int*)d_in[2];
  const float* W_in  = (const float*)d_in[3];
  const float* b_in  = (const float*)d_in[4];
  const float* W_mid = (const float*)d_in[5];
  const float* b_mid = (const float*)d_in[6];
  const float* W_mlp = (const float*)d_in[7];
  const float* b_mlp = (const float*)d_in[8];
  float* out = (float*)d_out;

  const int* src = ei;        // edge_index[0]
  const int* dst = ei + NE;   // edge_index[1]

  char* ws = (char*)d_ws;
  float* P       = (float*)ws;                       ws += (size_t)NN * FD * 4;  // 51.2 MB
  float* Q       = (float*)ws;                       ws += (size_t)NN * FD * 4;  // 51.2 MB
  float* dinv    = (float*)ws;                       ws += (size_t)NN * 4;
  int*   rowptr  = (int*)ws;                         ws += (size_t)(NN + 1) * 4;
  int*   cursor  = (int*)ws;                         ws += (size_t)NN * 4;
  int*   csr_src = (int*)ws;                         ws += (size_t)NE * 4;       // 6.4 MB
  float* sums    = (float*)ws;                       ws += (size_t)NG * FD * 4;
  float* counts  = (float*)ws;                       ws += (size_t)NG * 4;

  // CSR build (once; reused by all 4 layers)
  k_zero_int<<<(NN + 255) / 256, 256, 0, stream>>>(cursor, NN);
  k_count<<<(NE + 255) / 256, 256, 0, stream>>>(dst, cursor);
  k_scan<<<1, SCAN_T, 0, stream>>>(cursor, rowptr, dinv);
  k_fill<<<(NE + 255) / 256, 256, 0, stream>>>(src, dst, rowptr, cursor, csr_src);

  const int gN = (NN * FD + 255) / 256;   // 50000
  const int gG = (NN + 3) / 4;            // 25000 (4 waves/block, 1 node/wave)
  for (int L = 0; L < 4; ++L) {
    const float* X = (L == 0) ? x : P;
    const float* W = (L == 0) ? W_in : W_mid;
    const float* b = (L == 0) ? b_in : b_mid;
    k_gemm<<<gN, 256, 0, stream>>>(X, W, Q);
    k_gather<<<gG, 256, 0, stream>>>(rowptr, csr_src, dinv, Q, b, P);
  }

  k_zero_pool<<<32, 256, 0, stream>>>(sums, counts);
  k_pool<<<POOL_BLOCKS, 128, 0, stream>>>(batch, P, sums, counts);
  k_head<<<(NG * NC + 255) / 256, 256, 0, stream>>>(sums, counts, W_mlp, b_mlp, out);
}

// Round 3
// 1277.281 us; speedup vs baseline: 9.7579x; 2.0084x over previous
//
#include <hip/hip_runtime.h>

#define NN 100000
#define NE 1600000
#define FD 128
#define NC 10
#define NG 64

// ---------- CSR build ----------

__global__ void k_zero_int(int* __restrict__ a, int n) {
  int i = blockIdx.x * 256 + threadIdx.x;
  if (i < n) a[i] = 0;
}

__global__ void k_count(const int* __restrict__ dst, int* __restrict__ cnt) {
  int e = blockIdx.x * 256 + threadIdx.x;
  if (e < NE) atomicAdd(&cnt[dst[e]], 1);
}

// Single-block exclusive scan of in-degree counts -> rowptr; also emits
// dinv[i] = 1/sqrt(deg+1) and zeroes counts for reuse as the fill cursor.
#define SCAN_T 1024
#define SCAN_CHUNK 98  // 1024*98 = 100352 >= NN
__global__ void k_scan(int* __restrict__ cnt, int* __restrict__ rowptr,
                       float* __restrict__ dinv) {
  __shared__ int part[SCAN_T];
  int t = threadIdx.x;
  int c0 = t * SCAN_CHUNK;
  int c1 = c0 + SCAN_CHUNK; if (c1 > NN) c1 = NN;
  int s = 0;
  for (int i = c0; i < c1; ++i) s += cnt[i];
  part[t] = s;
  __syncthreads();
  for (int off = 1; off < SCAN_T; off <<= 1) {
    int v = (t >= off) ? part[t - off] : 0;
    __syncthreads();
    part[t] += v;
    __syncthreads();
  }
  int run = (t == 0) ? 0 : part[t - 1];
  for (int i = c0; i < c1; ++i) {
    int c = cnt[i];
    rowptr[i] = run;
    dinv[i] = rsqrtf((float)c + 1.0f);
    cnt[i] = 0;           // becomes the fill cursor
    run += c;
  }
  if (t == SCAN_T - 1) rowptr[NN] = run;
}

__global__ void k_fill(const int* __restrict__ src, const int* __restrict__ dst,
                       const int* __restrict__ rowptr, int* __restrict__ cursor,
                       const float* __restrict__ dinv,
                       int* __restrict__ csr_src, float* __restrict__ csr_w) {
  int e = blockIdx.x * 256 + threadIdx.x;
  if (e >= NE) return;
  int d = dst[e], s = src[e];
  int slot = rowptr[d] + atomicAdd(&cursor[d], 1);
  csr_src[slot] = s;
  csr_w[slot] = dinv[s] * dinv[d];
}

// ---------- GEMM: H = X @ W ----------
// 256 threads/block; W (128x128 = 64 KiB) staged in LDS; 64-row tile;
// each thread computes a 4-row x 8-col register tile. FMA:LDS = 32:2 per k.
__global__ void k_gemm(const float* __restrict__ X, const float* __restrict__ W,
                       float* __restrict__ H) {
  __shared__ float Wl[FD][FD];  // 64 KiB
  int tid = threadIdx.x;
  {
    const float4* __restrict__ Wv = (const float4*)W;
    float4* Wlv = (float4*)&Wl[0][0];
#pragma unroll
    for (int i = 0; i < FD * FD / 4 / 256; ++i)
      Wlv[tid + i * 256] = Wv[tid + i * 256];
  }
  __syncthreads();

  int row0 = blockIdx.x * 64 + (tid >> 4) * 4;   // 16 row-groups x 4 rows
  int col0 = (tid & 15) * 8;                     // 16 col-groups x 8 cols

  const float* xp[4];
#pragma unroll
  for (int r = 0; r < 4; ++r) {
    int rr = row0 + r;
    if (rr >= NN) rr = NN - 1;                   // clamp (tail block): reads valid mem
    xp[r] = X + (size_t)rr * FD;
  }

  float acc[4][8] = {};
  for (int kc = 0; kc < FD; kc += 4) {
    float xr[4][4];
#pragma unroll
    for (int r = 0; r < 4; ++r)
      *(float4*)xr[r] = *(const float4*)(xp[r] + kc);
#pragma unroll
    for (int kk = 0; kk < 4; ++kk) {
      float w[8];
      *(float4*)&w[0] = *(const float4*)&Wl[kc + kk][col0];
      *(float4*)&w[4] = *(const float4*)&Wl[kc + kk][col0 + 4];
#pragma unroll
      for (int r = 0; r < 4; ++r) {
        float xv = xr[r][kk];
#pragma unroll
        for (int c = 0; c < 8; ++c) acc[r][c] = fmaf(xv, w[c], acc[r][c]);
      }
    }
  }

#pragma unroll
  for (int r = 0; r < 4; ++r) {
    int rr = row0 + r;
    if (rr < NN) {
      float* hp = H + (size_t)rr * FD + col0;
      *(float4*)hp = *(float4*)&acc[r][0];
      *(float4*)(hp + 4) = *(float4*)&acc[r][4];
    }
  }
}

// ---------- gather: OUT[i] = relu(dinv_i^2*H[i] + b + sum_e w_e * H[src_e]) ----------
// 32 lanes per node (float4/lane), 2 nodes per wave, 8 nodes per block.
__global__ void k_gather(const int* __restrict__ rowptr, const int* __restrict__ csr_src,
                         const float* __restrict__ csr_w, const float* __restrict__ dinv,
                         const float* __restrict__ H, const float* __restrict__ b,
                         float* __restrict__ OUT) {
  int node = blockIdx.x * 8 + (threadIdx.x >> 5);
  if (node >= NN) return;
  int lane = threadIdx.x & 31;
  const float4* __restrict__ H4 = (const float4*)H;
  float di = dinv[node];
  float4 hv = H4[(size_t)node * 32 + lane];
  float4 bv = ((const float4*)b)[lane];
  float4 acc;
  float dii = di * di;
  acc.x = fmaf(dii, hv.x, bv.x);
  acc.y = fmaf(dii, hv.y, bv.y);
  acc.z = fmaf(dii, hv.z, bv.z);
  acc.w = fmaf(dii, hv.w, bv.w);
  int e0 = rowptr[node], e1 = rowptr[node + 1];
  int e = e0;
  for (; e + 1 < e1; e += 2) {            // 2 independent loads in flight
    int s0 = csr_src[e], s1 = csr_src[e + 1];
    float w0 = csr_w[e], w1 = csr_w[e + 1];
    float4 v0 = H4[(size_t)s0 * 32 + lane];
    float4 v1 = H4[(size_t)s1 * 32 + lane];
    acc.x = fmaf(w0, v0.x, acc.x); acc.y = fmaf(w0, v0.y, acc.y);
    acc.z = fmaf(w0, v0.z, acc.z); acc.w = fmaf(w0, v0.w, acc.w);
    acc.x = fmaf(w1, v1.x, acc.x); acc.y = fmaf(w1, v1.y, acc.y);
    acc.z = fmaf(w1, v1.z, acc.z); acc.w = fmaf(w1, v1.w, acc.w);
  }
  if (e < e1) {
    int s0 = csr_src[e];
    float w0 = csr_w[e];
    float4 v0 = H4[(size_t)s0 * 32 + lane];
    acc.x = fmaf(w0, v0.x, acc.x); acc.y = fmaf(w0, v0.y, acc.y);
    acc.z = fmaf(w0, v0.z, acc.z); acc.w = fmaf(w0, v0.w, acc.w);
  }
  acc.x = fmaxf(acc.x, 0.f); acc.y = fmaxf(acc.y, 0.f);
  acc.z = fmaxf(acc.z, 0.f); acc.w = fmaxf(acc.w, 0.f);
  ((float4*)OUT)[(size_t)node * 32 + lane] = acc;
}

// ---------- pooling + head ----------

__global__ void k_zero_pool(float* __restrict__ sums, float* __restrict__ counts) {
  int t = blockIdx.x * 256 + threadIdx.x;
  if (t < NG * FD) sums[t] = 0.f;
  if (t < NG) counts[t] = 0.f;
}

#define POOL_BLOCKS 1024
#define POOL_CHUNK 98
__global__ void k_pool(const int* __restrict__ batch, const float* __restrict__ H,
                       float* __restrict__ sums, float* __restrict__ counts) {
  int f = threadIdx.x;  // 0..127
  int i0 = blockIdx.x * POOL_CHUNK;
  if (i0 >= NN) return;
  int i1 = i0 + POOL_CHUNK;
  if (i1 > NN) i1 = NN;
  float acc = 0.f;
  int gcur = batch[i0];
  int cnt = 0;
  for (int i = i0; i < i1; ++i) {
    int g = batch[i];
    if (g != gcur) {
      atomicAdd(&sums[gcur * FD + f], acc);
      if (f == 0) atomicAdd(&counts[gcur], (float)cnt);
      acc = 0.f; cnt = 0; gcur = g;
    }
    acc += H[(size_t)i * FD + f];
    ++cnt;
  }
  atomicAdd(&sums[gcur * FD + f], acc);
  if (f == 0) atomicAdd(&counts[gcur], (float)cnt);
}

__global__ void k_head(const float* __restrict__ sums, const float* __restrict__ counts,
                       const float* __restrict__ Wm, const float* __restrict__ bm,
                       float* __restrict__ out) {
  int t = blockIdx.x * 256 + threadIdx.x;
  if (t >= NG * NC) return;
  int g = t / NC, c = t % NC;
  float inv = 1.0f / fmaxf(counts[g], 1.0f);
  float s = 0.f;
#pragma unroll 4
  for (int f = 0; f < FD; ++f) s = fmaf(sums[g * FD + f] * inv, Wm[f * NC + c], s);
  out[t] = s + bm[c];
}

extern "C" void kernel_launch(void* const* d_in, const int* in_sizes, int n_in,
                              void* d_out, int out_size, void* d_ws, size_t ws_size,
                              hipStream_t stream) {
  const float* x     = (const float*)d_in[0];
  const int*   ei    = (const int*)d_in[1];
  const int*   batch = (const int*)d_in[2];
  const float* W_in  = (const float*)d_in[3];
  const float* b_in  = (const float*)d_in[4];
  const float* W_mid = (const float*)d_in[5];
  const float* b_mid = (const float*)d_in[6];
  const float* W_mlp = (const float*)d_in[7];
  const float* b_mlp = (const float*)d_in[8];
  float* out = (float*)d_out;

  const int* src = ei;        // edge_index[0]
  const int* dst = ei + NE;   // edge_index[1]

  char* ws = (char*)d_ws;
  float* P       = (float*)ws;  ws += (size_t)NN * FD * 4;   // 51.2 MB
  float* Q       = (float*)ws;  ws += (size_t)NN * FD * 4;   // 51.2 MB
  float* dinv    = (float*)ws;  ws += (size_t)NN * 4;
  int*   rowptr  = (int*)ws;    ws += (size_t)(NN + 1) * 4;
  int*   cursor  = (int*)ws;    ws += (size_t)NN * 4;
  int*   csr_src = (int*)ws;    ws += (size_t)NE * 4;        // 6.4 MB
  float* csr_w   = (float*)ws;  ws += (size_t)NE * 4;        // 6.4 MB
  float* sums    = (float*)ws;  ws += (size_t)NG * FD * 4;
  float* counts  = (float*)ws;  ws += (size_t)NG * 4;

  // CSR build (once; reused by all 4 layers)
  k_zero_int<<<(NN + 255) / 256, 256, 0, stream>>>(cursor, NN);
  k_count<<<(NE + 255) / 256, 256, 0, stream>>>(dst, cursor);
  k_scan<<<1, SCAN_T, 0, stream>>>(cursor, rowptr, dinv);
  k_fill<<<(NE + 255) / 256, 256, 0, stream>>>(src, dst, rowptr, cursor, dinv,
                                               csr_src, csr_w);

  const int gM = (NN + 63) / 64;   // 1563 blocks, 64 rows each
  const int gG = (NN + 7) / 8;     // 12500 blocks, 8 nodes each
  for (int L = 0; L < 4; ++L) {
    const float* X = (L == 0) ? x : P;
    const float* W = (L == 0) ? W_in : W_mid;
    const float* b = (L == 0) ? b_in : b_mid;
    k_gemm<<<gM, 256, 0, stream>>>(X, W, Q);
    k_gather<<<gG, 256, 0, stream>>>(rowptr, csr_src, csr_w, dinv, Q, b, P);
  }

  k_zero_pool<<<32, 256, 0, stream>>>(sums, counts);
  k_pool<<<POOL_BLOCKS, 128, 0, stream>>>(batch, P, sums, counts);
  k_head<<<(NG * NC + 255) / 256, 256, 0, stream>>>(sums, counts, W_mlp, b_mlp, out);
}

// Round 4
// 1008.575 us; speedup vs baseline: 12.3576x; 1.2664x over previous
//
#include <hip/hip_runtime.h>

#define NN 100000
#define NE 1600000
#define FD 128
#define NC 10
#define NG 64

// ---------- CSR build ----------

__global__ void k_zero_int(int* __restrict__ a, int n) {
  int i = blockIdx.x * 256 + threadIdx.x;
  if (i < n) a[i] = 0;
}

__global__ void k_count(const int* __restrict__ dst, int* __restrict__ cnt) {
  int e = blockIdx.x * 256 + threadIdx.x;
  if (e < NE) atomicAdd(&cnt[dst[e]], 1);
}

// Parallel 3-phase exclusive scan of cnt[NN] -> rowptr; emits dinv and zeroes cnt.
#define NB_SCAN 196       // 196 * 512 = 100352 >= NN
#define SCH 2             // elements per thread (256 threads * 2 = 512/block)

__global__ void k_scanA(const int* __restrict__ cnt, int* __restrict__ blockSums) {
  __shared__ int red[256];
  int t = threadIdx.x, b = blockIdx.x;
  int i0 = b * 512 + t * SCH;
  int s = 0;
#pragma unroll
  for (int j = 0; j < SCH; ++j) { int i = i0 + j; if (i < NN) s += cnt[i]; }
  red[t] = s;
  __syncthreads();
  for (int off = 128; off > 0; off >>= 1) {
    if (t < off) red[t] += red[t + off];
    __syncthreads();
  }
  if (t == 0) blockSums[b] = red[0];
}

__global__ void k_scanB(const int* __restrict__ blockSums, int* __restrict__ blockOffs,
                        int* __restrict__ rowptr) {
  __shared__ int sh[256];
  int t = threadIdx.x;
  int v = (t < NB_SCAN) ? blockSums[t] : 0;
  sh[t] = v;
  __syncthreads();
  for (int off = 1; off < 256; off <<= 1) {
    int u = (t >= off) ? sh[t - off] : 0;
    __syncthreads();
    sh[t] += u;
    __syncthreads();
  }
  if (t < NB_SCAN) blockOffs[t] = sh[t] - v;   // exclusive
  if (t == 255) rowptr[NN] = sh[255];          // total edge count
}

__global__ void k_scanC(int* __restrict__ cnt, const int* __restrict__ blockOffs,
                        int* __restrict__ rowptr, float* __restrict__ dinv) {
  __shared__ int sh[256];
  int t = threadIdx.x, b = blockIdx.x;
  int i0 = b * 512 + t * SCH;
  int c[SCH];
  int s = 0;
#pragma unroll
  for (int j = 0; j < SCH; ++j) {
    int i = i0 + j;
    c[j] = (i < NN) ? cnt[i] : 0;
    s += c[j];
  }
  sh[t] = s;
  __syncthreads();
  for (int off = 1; off < 256; off <<= 1) {
    int u = (t >= off) ? sh[t - off] : 0;
    __syncthreads();
    sh[t] += u;
    __syncthreads();
  }
  int run = blockOffs[b] + sh[t] - s;          // exclusive prefix for this thread
#pragma unroll
  for (int j = 0; j < SCH; ++j) {
    int i = i0 + j;
    if (i < NN) {
      rowptr[i] = run;
      dinv[i] = rsqrtf((float)c[j] + 1.0f);
      cnt[i] = 0;                              // becomes the fill cursor
      run += c[j];
    }
  }
}

__global__ void k_fill(const int* __restrict__ src, const int* __restrict__ dst,
                       const int* __restrict__ rowptr, int* __restrict__ cursor,
                       const float* __restrict__ dinv,
                       int* __restrict__ csr_src, float* __restrict__ csr_w) {
  int e = blockIdx.x * 256 + threadIdx.x;
  if (e >= NE) return;
  int d = dst[e], s = src[e];
  int slot = rowptr[d] + atomicAdd(&cursor[d], 1);
  csr_src[slot] = s;
  csr_w[slot] = dinv[s] * dinv[d];
}

// ---------- GEMM: H = X @ W ----------
// 256 threads/block; W (128x128 = 64 KiB) staged in LDS; 64-row tile;
// each thread computes a 4-row x 8-col register tile.
__global__ void k_gemm(const float* __restrict__ X, const float* __restrict__ W,
                       float* __restrict__ H) {
  __shared__ float Wl[FD][FD];  // 64 KiB
  int tid = threadIdx.x;
  {
    const float4* __restrict__ Wv = (const float4*)W;
    float4* Wlv = (float4*)&Wl[0][0];
#pragma unroll
    for (int i = 0; i < FD * FD / 4 / 256; ++i)
      Wlv[tid + i * 256] = Wv[tid + i * 256];
  }
  __syncthreads();

  int row0 = blockIdx.x * 64 + (tid >> 4) * 4;
  int col0 = (tid & 15) * 8;

  const float* xp[4];
#pragma unroll
  for (int r = 0; r < 4; ++r) {
    int rr = row0 + r;
    if (rr >= NN) rr = NN - 1;
    xp[r] = X + (size_t)rr * FD;
  }

  float acc[4][8] = {};
  for (int kc = 0; kc < FD; kc += 4) {
    float xr[4][4];
#pragma unroll
    for (int r = 0; r < 4; ++r)
      *(float4*)xr[r] = *(const float4*)(xp[r] + kc);
#pragma unroll
    for (int kk = 0; kk < 4; ++kk) {
      float w[8];
      *(float4*)&w[0] = *(const float4*)&Wl[kc + kk][col0];
      *(float4*)&w[4] = *(const float4*)&Wl[kc + kk][col0 + 4];
#pragma unroll
      for (int r = 0; r < 4; ++r) {
        float xv = xr[r][kk];
#pragma unroll
        for (int c = 0; c < 8; ++c) acc[r][c] = fmaf(xv, w[c], acc[r][c]);
      }
    }
  }

#pragma unroll
  for (int r = 0; r < 4; ++r) {
    int rr = row0 + r;
    if (rr < NN) {
      float* hp = H + (size_t)rr * FD + col0;
      *(float4*)hp = *(float4*)&acc[r][0];
      *(float4*)(hp + 4) = *(float4*)&acc[r][4];
    }
  }
}

// ---------- gather: OUT[i] = relu(dinv_i^2*H[i] + b + sum_e w_e * H[src_e]) ----------
__global__ void k_gather(const int* __restrict__ rowptr, const int* __restrict__ csr_src,
                         const float* __restrict__ csr_w, const float* __restrict__ dinv,
                         const float* __restrict__ H, const float* __restrict__ b,
                         float* __restrict__ OUT) {
  int node = blockIdx.x * 8 + (threadIdx.x >> 5);
  if (node >= NN) return;
  int lane = threadIdx.x & 31;
  const float4* __restrict__ H4 = (const float4*)H;
  float di = dinv[node];
  float4 hv = H4[(size_t)node * 32 + lane];
  float4 bv = ((const float4*)b)[lane];
  float4 acc;
  float dii = di * di;
  acc.x = fmaf(dii, hv.x, bv.x);
  acc.y = fmaf(dii, hv.y, bv.y);
  acc.z = fmaf(dii, hv.z, bv.z);
  acc.w = fmaf(dii, hv.w, bv.w);
  int e0 = rowptr[node], e1 = rowptr[node + 1];
  int e = e0;
  for (; e + 1 < e1; e += 2) {
    int s0 = csr_src[e], s1 = csr_src[e + 1];
    float w0 = csr_w[e], w1 = csr_w[e + 1];
    float4 v0 = H4[(size_t)s0 * 32 + lane];
    float4 v1 = H4[(size_t)s1 * 32 + lane];
    acc.x = fmaf(w0, v0.x, acc.x); acc.y = fmaf(w0, v0.y, acc.y);
    acc.z = fmaf(w0, v0.z, acc.z); acc.w = fmaf(w0, v0.w, acc.w);
    acc.x = fmaf(w1, v1.x, acc.x); acc.y = fmaf(w1, v1.y, acc.y);
    acc.z = fmaf(w1, v1.z, acc.z); acc.w = fmaf(w1, v1.w, acc.w);
  }
  if (e < e1) {
    int s0 = csr_src[e];
    float w0 = csr_w[e];
    float4 v0 = H4[(size_t)s0 * 32 + lane];
    acc.x = fmaf(w0, v0.x, acc.x); acc.y = fmaf(w0, v0.y, acc.y);
    acc.z = fmaf(w0, v0.z, acc.z); acc.w = fmaf(w0, v0.w, acc.w);
  }
  acc.x = fmaxf(acc.x, 0.f); acc.y = fmaxf(acc.y, 0.f);
  acc.z = fmaxf(acc.z, 0.f); acc.w = fmaxf(acc.w, 0.f);
  ((float4*)OUT)[(size_t)node * 32 + lane] = acc;
}

// ---------- pooling + head ----------

__global__ void k_zero_pool(float* __restrict__ sums, float* __restrict__ counts) {
  int t = blockIdx.x * 256 + threadIdx.x;
  if (t < NG * FD) sums[t] = 0.f;
  if (t < NG) counts[t] = 0.f;
}

#define POOL_BLOCKS 1024
#define POOL_CHUNK 98
__global__ void k_pool(const int* __restrict__ batch, const float* __restrict__ H,
                       float* __restrict__ sums, float* __restrict__ counts) {
  int f = threadIdx.x;  // 0..127
  int i0 = blockIdx.x * POOL_CHUNK;
  if (i0 >= NN) return;
  int i1 = i0 + POOL_CHUNK;
  if (i1 > NN) i1 = NN;
  float acc = 0.f;
  int gcur = batch[i0];
  int cnt = 0;
  for (int i = i0; i < i1; ++i) {
    int g = batch[i];
    if (g != gcur) {
      atomicAdd(&sums[gcur * FD + f], acc);
      if (f == 0) atomicAdd(&counts[gcur], (float)cnt);
      acc = 0.f; cnt = 0; gcur = g;
    }
    acc += H[(size_t)i * FD + f];
    ++cnt;
  }
  atomicAdd(&sums[gcur * FD + f], acc);
  if (f == 0) atomicAdd(&counts[gcur], (float)cnt);
}

__global__ void k_head(const float* __restrict__ sums, const float* __restrict__ counts,
                       const float* __restrict__ Wm, const float* __restrict__ bm,
                       float* __restrict__ out) {
  int t = blockIdx.x * 256 + threadIdx.x;
  if (t >= NG * NC) return;
  int g = t / NC, c = t % NC;
  float inv = 1.0f / fmaxf(counts[g], 1.0f);
  float s = 0.f;
#pragma unroll 4
  for (int f = 0; f < FD; ++f) s = fmaf(sums[g * FD + f] * inv, Wm[f * NC + c], s);
  out[t] = s + bm[c];
}

extern "C" void kernel_launch(void* const* d_in, const int* in_sizes, int n_in,
                              void* d_out, int out_size, void* d_ws, size_t ws_size,
                              hipStream_t stream) {
  const float* x     = (const float*)d_in[0];
  const int*   ei    = (const int*)d_in[1];
  const int*   batch = (const int*)d_in[2];
  const float* W_in  = (const float*)d_in[3];
  const float* b_in  = (const float*)d_in[4];
  const float* W_mid = (const float*)d_in[5];
  const float* b_mid = (const float*)d_in[6];
  const float* W_mlp = (const float*)d_in[7];
  const float* b_mlp = (const float*)d_in[8];
  float* out = (float*)d_out;

  const int* src = ei;        // edge_index[0]
  const int* dst = ei + NE;   // edge_index[1]

  char* ws = (char*)d_ws;
  float* P         = (float*)ws;  ws += (size_t)NN * FD * 4;   // 51.2 MB
  float* Q         = (float*)ws;  ws += (size_t)NN * FD * 4;   // 51.2 MB
  float* dinv      = (float*)ws;  ws += (size_t)NN * 4;
  int*   rowptr    = (int*)ws;    ws += (size_t)(NN + 1) * 4;
  int*   cursor    = (int*)ws;    ws += (size_t)NN * 4;
  int*   csr_src   = (int*)ws;    ws += (size_t)NE * 4;        // 6.4 MB
  float* csr_w     = (float*)ws;  ws += (size_t)NE * 4;        // 6.4 MB
  int*   blockSums = (int*)ws;    ws += 256 * 4;
  int*   blockOffs = (int*)ws;    ws += 256 * 4;
  float* sums      = (float*)ws;  ws += (size_t)NG * FD * 4;
  float* counts    = (float*)ws;  ws += (size_t)NG * 4;

  // CSR build (reused by all 4 layers)
  k_zero_int<<<(NN + 255) / 256, 256, 0, stream>>>(cursor, NN);
  k_count<<<(NE + 255) / 256, 256, 0, stream>>>(dst, cursor);
  k_scanA<<<NB_SCAN, 256, 0, stream>>>(cursor, blockSums);
  k_scanB<<<1, 256, 0, stream>>>(blockSums, blockOffs, rowptr);
  k_scanC<<<NB_SCAN, 256, 0, stream>>>(cursor, blockOffs, rowptr, dinv);
  k_fill<<<(NE + 255) / 256, 256, 0, stream>>>(src, dst, rowptr, cursor, dinv,
                                               csr_src, csr_w);

  const int gM = (NN + 63) / 64;   // 1563 blocks, 64 rows each
  const int gG = (NN + 7) / 8;     // 12500 blocks, 8 nodes each
  for (int L = 0; L < 4; ++L) {
    const float* X = (L == 0) ? x : P;
    const float* W = (L == 0) ? W_in : W_mid;
    const float* b = (L == 0) ? b_in : b_mid;
    k_gemm<<<gM, 256, 0, stream>>>(X, W, Q);
    k_gather<<<gG, 256, 0, stream>>>(rowptr, csr_src, csr_w, dinv, Q, b, P);
  }

  k_zero_pool<<<32, 256, 0, stream>>>(sums, counts);
  k_pool<<<POOL_BLOCKS, 128, 0, stream>>>(batch, P, sums, counts);
  k_head<<<(NG * NC + 255) / 256, 256, 0, stream>>>(sums, counts, W_mlp, b_mlp, out);
}